// Round 1
// baseline (222.463 us; speedup 1.0000x reference)
//
#include <hip/hip_runtime.h>
#include <hip/hip_bf16.h>

#define NUM_CLASSES 80
#define BATCH 8
#define N20 1200
#define N40 4800
#define N80 19200
#define NANCH 25200           // N20+N40+N80
#define NEGV  -1000000000.0f
#define SCORE_THR 0.25f
#define NBINS 4096
#define CAPC 4096
#define PF 512

// ---------------------------------------------------------------------------
// Kernel 1: per-anchor class argmax + score + box gather.
// 4 threads per anchor; each handles 20 classes via 5 float4 loads.
// ---------------------------------------------------------------------------
__global__ void score_kernel(const float* __restrict__ b20, const float* __restrict__ p20, const float* __restrict__ c20,
                             const float* __restrict__ b40, const float* __restrict__ p40, const float* __restrict__ c40,
                             const float* __restrict__ b80, const float* __restrict__ p80, const float* __restrict__ c80,
                             float* __restrict__ scores, float4* __restrict__ boxes) {
    int gid = blockIdx.x * blockDim.x + threadIdx.x;
    int q  = gid & 3;
    int an = gid >> 2;                      // global anchor id in [0, BATCH*NANCH)
    if (an >= BATCH * NANCH) return;
    int b = an / NANCH;
    int n = an - b * NANCH;

    const float *cp, *pp, *bp;
    if (n < N20) {
        int a = n;
        cp = c20 + (size_t)(b * N20 + a) * NUM_CLASSES;
        pp = p20 + (size_t)b * N20 + a;
        bp = b20 + (size_t)(b * N20 + a) * 4;
    } else if (n < N20 + N40) {
        int a = n - N20;
        cp = c40 + (size_t)(b * N40 + a) * NUM_CLASSES;
        pp = p40 + (size_t)b * N40 + a;
        bp = b40 + (size_t)(b * N40 + a) * 4;
    } else {
        int a = n - N20 - N40;
        cp = c80 + (size_t)(b * N80 + a) * NUM_CLASSES;
        pp = p80 + (size_t)b * N80 + a;
        bp = b80 + (size_t)(b * N80 + a) * 4;
    }

    const float4* c4 = (const float4*)cp;
    float best = -INFINITY;
    int bi = 0;
#pragma unroll
    for (int j = 0; j < 5; j++) {
        float4 v = c4[q * 5 + j];
        int base = q * 20 + j * 4;
        if (v.x > best) { best = v.x; bi = base; }
        if (v.y > best) { best = v.y; bi = base + 1; }
        if (v.z > best) { best = v.z; bi = base + 2; }
        if (v.w > best) { best = v.w; bi = base + 3; }
    }
    // combine across the 4 threads of this anchor (lanes differ in bits 0,1).
    // tie-break: smaller class index wins (np.argmax first-max semantics).
#pragma unroll
    for (int d = 1; d <= 2; d <<= 1) {
        float ov = __shfl_xor(best, d);
        int   oi = __shfl_xor(bi, d);
        if (ov > best || (ov == best && oi < bi)) { best = ov; bi = oi; }
    }
    if (q == 0) {
        float p = *pp;
        float scv = __fmul_rn(p, (float)bi);           // exact, matches np float32 mul
        scores[an] = (scv > SCORE_THR) ? scv : NEGV;
        boxes[an]  = *(const float4*)bp;
    }
}

// Exact (IEEE fp32, no FMA contraction) "IoU > 0.5" per reference/numpy:
//   ih = max(min(y2,Y2)-max(y1,Y1),0); iw likewise
//   inter = ih*iw; union = areaA + areaB - inter
//   iou = union>0 ? inter/union : 0 ;  suppressed iff iou > 0.5
// box layout: .x=y1 .y=x1 .z=y2 .w=x2 ; areaA = survivor area (first addend).
__device__ __forceinline__ bool iou_gt(const float4 A, float areaA, const float4 Bx, float areaB) {
    float ih = fmaxf(__fsub_rn(fminf(A.z, Bx.z), fmaxf(A.x, Bx.x)), 0.0f);
    float iw = fmaxf(__fsub_rn(fminf(A.w, Bx.w), fmaxf(A.y, Bx.y)), 0.0f);
    float inter = __fmul_rn(ih, iw);
    float uni = __fsub_rn(__fadd_rn(areaA, areaB), inter);
    if (!(uni > 0.0f)) return false;
    return __fdiv_rn(inter, uni) > 0.5f;
}

// ---------------------------------------------------------------------------
// Kernel 2: exact greedy NMS via sorted-order walk. One block per batch.
// ---------------------------------------------------------------------------
__global__ __launch_bounds__(1024) void nms_kernel(const float* __restrict__ scores_g,
                                                   const float4* __restrict__ boxes_g,
                                                   float* __restrict__ out) {
    __shared__ unsigned hist[NBINS];          // becomes suffix sums Ssuf[b]
    __shared__ unsigned segT[1024];
    __shared__ unsigned long long keys[CAPC];
    __shared__ float4 candbox[PF];
    __shared__ int sh_lo, sh_hi, sh_V;
    __shared__ unsigned sh_counter, sh_done, sh_total;

    const int t = threadIdx.x;
    const int b = blockIdx.x;
    const float*  sc = scores_g + (size_t)b * NANCH;
    const float4* bx = boxes_g + (size_t)b * NANCH;

    for (int i = t; i < NBINS; i += 1024) hist[i] = 0u;
    if (t == 0) { sh_V = 0; sh_done = 0u; sh_hi = NBINS; }
    __syncthreads();

    // histogram over top-12 bits of score float bits (monotone for positives)
    for (int i = t; i < NANCH; i += 1024) {
        float s = sc[i];
        if (s > SCORE_THR) atomicAdd(&hist[__float_as_uint(s) >> 20], 1u);
    }
    __syncthreads();

    // suffix sums: thread t owns bins [4t, 4t+3]
    unsigned h0 = hist[4 * t + 0], h1 = hist[4 * t + 1], h2 = hist[4 * t + 2], h3 = hist[4 * t + 3];
    segT[t] = h0 + h1 + h2 + h3;
    __syncthreads();
    for (int d = 1; d < 1024; d <<= 1) {
        unsigned vv = (t + d < 1024) ? segT[t + d] : 0u;
        __syncthreads();
        segT[t] += vv;
        __syncthreads();
    }
    {
        unsigned carry = (t < 1023) ? segT[t + 1] : 0u;
        unsigned s3 = h3 + carry, s2 = h2 + s3, s1 = h1 + s2, s0 = h0 + s1;
        hist[4 * t + 0] = s0; hist[4 * t + 1] = s1; hist[4 * t + 2] = s2; hist[4 * t + 3] = s3;
    }
    __syncthreads();
    if (t == 0) sh_total = hist[0];

    // survivor state: lane l of wave 0 holds survivors l and l+64 (<=100 total)
    float4 sb0 = make_float4(0.f, 0.f, 0.f, 0.f), sb1 = sb0;
    float sa0 = 0.f, sa1 = 0.f;
    int v = 0;   // live in wave 0 only

    for (int chunk = 0; chunk < 64; chunk++) {
        __syncthreads();
        if (sh_V >= 100 || sh_done >= sh_total) break;
        const int hi = sh_hi;
        const unsigned Shi = (hi >= NBINS) ? 0u : hist[hi];
        if (t == 0) {
            // minimal lo with Ssuf[lo]-Shi <= CAPC  (Ssuf non-increasing)
            int L = 0, R = hi;
            while (L < R) { int m = (L + R) >> 1; if (hist[m] - Shi <= (unsigned)CAPC) R = m; else L = m + 1; }
            if (L >= hi) L = hi - 1;   // pathological single-bin overflow guard
            sh_lo = L;
            sh_counter = 0u;
        }
        __syncthreads();
        const int lo = sh_lo;

        // collect candidates with bin in [lo, hi)
        for (int i = t; i < NANCH; i += 1024) {
            float s = sc[i];
            if (s > SCORE_THR) {
                int bin = (int)(__float_as_uint(s) >> 20);
                if (bin >= lo && bin < hi) {
                    unsigned pos = atomicAdd(&sh_counter, 1u);
                    if (pos < (unsigned)CAPC)
                        keys[pos] = ((unsigned long long)__float_as_uint(s) << 32)
                                  | (unsigned long long)(0xFFFFFFFFu - (unsigned)i);
                }
            }
        }
        __syncthreads();
        const int cnt = min((int)sh_counter, CAPC);
        int M = 2; while (M < cnt) M <<= 1;
        for (int i = cnt + t; i < M; i += 1024) keys[i] = 0ull;
        __syncthreads();

        // bitonic sort, descending (score desc, idx asc via ~idx in low word)
        for (int k = 2; k <= M; k <<= 1) {
            for (int j = k >> 1; j > 0; j >>= 1) {
                for (int i = t; i < M; i += 1024) {
                    int ixj = i ^ j;
                    if (ixj > i) {
                        unsigned long long a = keys[i], c = keys[ixj];
                        bool desc = ((i & k) == 0);
                        if (desc ? (a < c) : (a > c)) { keys[i] = c; keys[ixj] = a; }
                    }
                }
                __syncthreads();
            }
        }

        // walk in sorted order; wave 0 only, windows of PF prefetched boxes
        const int nwin = (cnt + PF - 1) / PF;
        for (int w = 0; w < nwin; w++) {
            if (sh_V >= 100) break;
            const int base = w * PF;
            const int lim = min(cnt, base + PF);
            for (int i = base + t; i < lim; i += 1024) {
                unsigned idx = 0xFFFFFFFFu - (unsigned)(keys[i] & 0xFFFFFFFFull);
                candbox[i - base] = bx[idx];
            }
            __syncthreads();
            if (t < 64) {
                for (int i = base; i < lim && v < 100; i++) {
                    const unsigned long long key = keys[i];
                    const float s = __uint_as_float((unsigned)(key >> 32));
                    const float4 cb = candbox[i - base];
                    const float areaB = __fmul_rn(__fsub_rn(cb.z, cb.x), __fsub_rn(cb.w, cb.y));
                    bool sup = false;
                    if (t < v)      sup = iou_gt(sb0, sa0, cb, areaB);
                    if (t + 64 < v) sup = sup || iou_gt(sb1, sa1, cb, areaB);
                    if (!__any(sup)) {
                        if (v < 64) { if (t == v)      { sb0 = cb; sa0 = areaB; } }
                        else        { if (t == v - 64) { sb1 = cb; sa1 = areaB; } }
                        if (t == 0) {
                            float* row = out + (size_t)(b * 100 + v) * 6;
                            row[0] = fminf(fmaxf(cb.x, 0.f), 1.f);
                            row[1] = fminf(fmaxf(cb.y, 0.f), 1.f);
                            row[2] = fminf(fmaxf(cb.z, 0.f), 1.f);
                            row[3] = fminf(fmaxf(cb.w, 0.f), 1.f);
                            row[4] = s;
                            row[5] = 0.f;
                        }
                        v++;
                    }
                }
                if (t == 0) sh_V = v;
            }
            __syncthreads();
        }
        __syncthreads();
        if (t == 0) { sh_done += (unsigned)cnt; sh_hi = lo; }
    }
    __syncthreads();

    const int V = sh_V;
    for (int i = V * 6 + t; i < 600; i += 1024) out[(size_t)b * 600 + i] = 0.f;
    if (t == 0) out[4800 + b] = (float)V;
}

extern "C" void kernel_launch(void* const* d_in, const int* in_sizes, int n_in,
                              void* d_out, int out_size, void* d_ws, size_t ws_size,
                              hipStream_t stream) {
    const float* b20 = (const float*)d_in[0];
    const float* p20 = (const float*)d_in[1];
    const float* c20 = (const float*)d_in[2];
    const float* b40 = (const float*)d_in[3];
    const float* p40 = (const float*)d_in[4];
    const float* c40 = (const float*)d_in[5];
    const float* b80 = (const float*)d_in[6];
    const float* p80 = (const float*)d_in[7];
    const float* c80 = (const float*)d_in[8];

    float*  scores = (float*)d_ws;                                   // BATCH*NANCH floats
    float4* boxes  = (float4*)((char*)d_ws + (size_t)BATCH * NANCH * sizeof(float)); // 16B-aligned (806400 % 16 == 0)

    const int total_threads = BATCH * NANCH * 4;
    score_kernel<<<(total_threads + 255) / 256, 256, 0, stream>>>(
        b20, p20, c20, b40, p40, c40, b80, p80, c80, scores, boxes);

    nms_kernel<<<BATCH, 1024, 0, stream>>>(scores, boxes, (float*)d_out);
}